// Round 4
// baseline (338.759 us; speedup 1.0000x reference)
//
#include <hip/hip_runtime.h>

// Problem: N=4096, D=1024, C=1000, T=32
//   h = x @ W^T  (4096 x 2000), mu = h[:, :1000], logvar = h[:, 1000:]
//   sigma = exp(0.5*logvar)
//   eps = jax.random.normal(key(42), (32,4096,1000))  -- threefry2x32, bit-exact
//   prob = mean_t softmax(mu + sigma*eps), out0 = exp(prob), out1 = sigma

typedef __attribute__((ext_vector_type(8))) _Float16 f16x8;
typedef __attribute__((ext_vector_type(4))) float f32x4;
typedef __attribute__((ext_vector_type(2))) float f32x2;

#define NC_TOT  4096000
#define H_HALF  65536000u   // half of T*N*C = 131072000

// ---------------- fp32 -> fp16 (RNE) ----------------
__device__ __forceinline__ unsigned short f2h(float f) {
  _Float16 h = (_Float16)f;
  return __builtin_bit_cast(unsigned short, h);
}

__global__ __launch_bounds__(256) void convert_kernel(
    const float* __restrict__ x, const float* __restrict__ W,
    unsigned short* __restrict__ xh, unsigned short* __restrict__ wh) {
  int qid = blockIdx.x * 256 + threadIdx.x;
  if (qid < 1048576) {                        // x: 4096*1024/4
    float4 v = ((const float4*)x)[qid];
    ((ushort4*)xh)[qid] = make_ushort4(f2h(v.x), f2h(v.y), f2h(v.z), f2h(v.w));
  } else {
    int q = qid - 1048576;                    // padded W quad index, < 524288
    int row = q >> 8;
    ushort4 o;
    if (row < 2000) {
      float4 v = ((const float4*)W)[q];
      o = make_ushort4(f2h(v.x), f2h(v.y), f2h(v.z), f2h(v.w));
    } else {
      o = make_ushort4(0, 0, 0, 0);
    }
    ((ushort4*)wh)[q] = o;
  }
}

// ---------------- fp16 MFMA GEMM, m97 structure (unchanged from round 3) ----------------
#define BK 32

typedef __attribute__((address_space(3))) unsigned char lds_byte;
typedef __attribute__((address_space(1))) unsigned char glb_byte;

__device__ __forceinline__ void glds16(const unsigned short* g, unsigned short* l) {
  __builtin_amdgcn_global_load_lds((const glb_byte*)g, (lds_byte*)l, 16, 0, 0);
}

__global__ __launch_bounds__(256) void gemm_kernel(
    const unsigned short* __restrict__ Ah,    // [4096][1024] fp16 bits
    const unsigned short* __restrict__ Bh,    // [2048][1024] fp16 bits, padded
    float* __restrict__ mu,                   // [4096][1000]
    float* __restrict__ sigma_out) {          // d_out + NC_TOT
  const int K = 1024;
  __shared__ unsigned short As[128 * BK];
  __shared__ unsigned short Bs[128 * BK];

  int tid  = threadIdx.x;
  int bx   = blockIdx.x;
  int by   = blockIdx.y;
  int w    = tid >> 6;
  int lane = tid & 63;
  int wr   = (w >> 1) * 64;
  int wc   = (w & 1) * 64;
  int lrow = lane & 15;
  int kq   = lane >> 4;

  f32x4 acc[4][4];
  for (int i = 0; i < 4; i++)
    for (int j = 0; j < 4; j++) acc[i][j] = (f32x4){0.f, 0.f, 0.f, 0.f};

  int srow = w * 16 + (lane >> 2);
  int scol = (lane & 3) * 8;
  const unsigned short* Ap = Ah + (by * 128 + srow) * K + scol;
  const unsigned short* Bp = Bh + (bx * 128 + srow) * K + scol;
  unsigned short* lA = As + w * 512;
  unsigned short* lB = Bs + w * 512;

  for (int kk = 0; kk < K; kk += BK) {
    __syncthreads();
    glds16(Ap + kk,            lA);
    glds16(Ap + kk + 64 * K,   lA + 2048);
    glds16(Bp + kk,            lB);
    glds16(Bp + kk + 64 * K,   lB + 2048);
    __syncthreads();

    f16x8 a[4], b[4];
    for (int i = 0; i < 4; i++)
      a[i] = *(const f16x8*)(As + (wr + i * 16 + lrow) * BK + kq * 8);
    for (int j = 0; j < 4; j++)
      b[j] = *(const f16x8*)(Bs + (wc + j * 16 + lrow) * BK + kq * 8);
    for (int i = 0; i < 4; i++)
      for (int j = 0; j < 4; j++)
        acc[i][j] = __builtin_amdgcn_mfma_f32_16x16x32_f16(a[i], b[j], acc[i][j], 0, 0, 0);
  }

  int orow0 = by * 128 + wr + (lane >> 4) * 4;
  int ocol0 = bx * 128 + wc + (lane & 15);
  for (int i = 0; i < 4; i++) {
    for (int j = 0; j < 4; j++) {
      int c = ocol0 + j * 16;
      for (int v = 0; v < 4; v++) {
        int r = orow0 + i * 16 + v;
        float val = acc[i][j][v];
        if (c < 1000)       mu[r * 1000 + c] = val;
        else if (c < 2000)  sigma_out[r * 1000 + (c - 1000)] = __expf(0.5f * val);
      }
    }
  }
}

// ---------------- threefry2x32, key = (0, 42) ----------------
__device__ __forceinline__ void threefry(unsigned x0, unsigned x1,
                                         unsigned& o0, unsigned& o1) {
  const unsigned ks1 = 42u;
  const unsigned ks2 = 0x1BD11BDAu ^ 42u;
#define TF_RND(r) { x0 += x1; x1 = (x1 << (r)) | (x1 >> (32 - (r))); x1 ^= x0; }
  x1 += ks1;
  TF_RND(13) TF_RND(15) TF_RND(26) TF_RND(6)
  x0 += ks1;  x1 += ks2 + 1u;
  TF_RND(17) TF_RND(29) TF_RND(16) TF_RND(24)
  x0 += ks2;  x1 += 2u;
  TF_RND(13) TF_RND(15) TF_RND(26) TF_RND(6)
  x1 += ks1 + 3u;
  TF_RND(17) TF_RND(29) TF_RND(16) TF_RND(24)
  x0 += ks1;  x1 += ks2 + 4u;
  TF_RND(13) TF_RND(15) TF_RND(26) TF_RND(6)
  x0 += ks2;  x1 += 5u;
#undef TF_RND
  o0 = x0; o1 = x1;
}

__device__ __forceinline__ float erfinv_big(float x, float w) {
  float v = __fsqrt_rn(w) - 3.0f;
  float p = -0.000200214257f;
  p = fmaf(p, v, 0.000100950558f);
  p = fmaf(p, v, 0.00134934322f);
  p = fmaf(p, v, -0.00367342844f);
  p = fmaf(p, v, 0.00573950773f);
  p = fmaf(p, v, -0.0076224613f);
  p = fmaf(p, v, 0.00943887047f);
  p = fmaf(p, v, 1.00167406f);
  p = fmaf(p, v, 2.83297682f);
  return 1.41421356f * (p * x);
}

__device__ __forceinline__ f32x2 splat2(float c) { return (f32x2){c, c}; }

__device__ __forceinline__ f32x2 normal2(f32x2 x) {
  f32x2 t = __builtin_elementwise_fma(-x, x, splat2(1.0f));
  f32x2 lg;
  lg.x = __builtin_amdgcn_logf(t.x);
  lg.y = __builtin_amdgcn_logf(t.y);
  f32x2 w = lg * splat2(-0.69314718f);
  f32x2 v = w - splat2(2.5f);
  f32x2 p = splat2(2.81022636e-08f);
  p = __builtin_elementwise_fma(p, v, splat2(3.43273939e-07f));
  p = __builtin_elementwise_fma(p, v, splat2(-3.5233877e-06f));
  p = __builtin_elementwise_fma(p, v, splat2(-4.39150654e-06f));
  p = __builtin_elementwise_fma(p, v, splat2(0.00021858087f));
  p = __builtin_elementwise_fma(p, v, splat2(-0.00125372503f));
  p = __builtin_elementwise_fma(p, v, splat2(-0.00417768164f));
  p = __builtin_elementwise_fma(p, v, splat2(0.246640727f));
  p = __builtin_elementwise_fma(p, v, splat2(1.50140941f));
  f32x2 r = (p * x) * splat2(1.41421356f);
  if (w.x >= 5.0f) r.x = erfinv_big(x.x, w.x);   // rare (~0.34%/sample)
  if (w.y >= 5.0f) r.y = erfinv_big(x.y, w.y);
  return r;
}

__device__ __forceinline__ f32x2 bits_to_u2(unsigned b0, unsigned b1) {
  f32x2 f;
  f.x = __builtin_bit_cast(float, (b0 >> 9) | 0x3f800000u);
  f.y = __builtin_bit_cast(float, (b1 >> 9) | 0x3f800000u);
  f = f - splat2(1.0f);
  return __builtin_elementwise_fma(f, splat2(2.0f), splat2(-0.99999994f));
}

// ---------------- sampling ----------------
// 512 thr = 8 waves per row n; wave w owns t-pairs {2w, 2w+1}; 16 chunks of 64.
// mu/sigma live in LDS (staged once, shared by all 8 waves) -> per-wave register
// state is only prob[16] + e[16], letting 6 waves/SIMD stay resident.
__global__ __launch_bounds__(512, 6) void sample_kernel(
    const float* __restrict__ mu,      // ws
    const float* __restrict__ sigma,   // d_out + NC
    float* __restrict__ out0) {        // d_out
  int n    = blockIdx.x;
  int tid  = threadIdx.x;
  int lane = tid & 63, w = tid >> 6;   // w in 0..7
  __shared__ float2 msb[1024];         // (mu, sigma) interleaved, 8 KB
  __shared__ float  pbuf[8][1024];     // per-wave prob partials, 32 KB

  int cb = n * 1000;
#pragma unroll
  for (int k = 0; k < 2; k++) {
    int c = tid + k * 512;
    float2 v;
    if (c < 1000) { v.x = mu[cb + c]; v.y = sigma[cb + c]; }
    else          { v.x = 0.f;        v.y = 0.f; }
    msb[c] = v;
  }
  __syncthreads();

  float prob[16];
#pragma unroll
  for (int j = 0; j < 16; j++) prob[j] = 0.f;

  f32x2 e[16];
#pragma unroll 1
  for (int it = 0; it < 2; it++) {
    int t = w * 2 + it;
    unsigned ib = (unsigned)(t * 4096000 + cb) + (unsigned)lane;
    f32x2 s = splat2(0.f);
#pragma unroll
    for (int j = 0; j < 16; j++) {
      float2 ms = msb[j * 64 + lane];            // stride-2 banks: free 2-way
      unsigned i0 = ib + (unsigned)(j * 64);
      unsigned o0, o1;
      threefry(i0, i0 + H_HALF, o0, o1);
      f32x2 eps = normal2(bits_to_u2(o0, o1));
      f32x2 lg = __builtin_elementwise_fma(splat2(ms.y), eps, splat2(ms.x));
      f32x2 ev;
      ev.x = __expf(lg.x);                       // sample t
      ev.y = __expf(lg.y);                       // sample t+16
      if (j == 15) {                             // classes >= 1000 are padding
        ev.x = (lane < 40) ? ev.x : 0.f;
        ev.y = (lane < 40) ? ev.y : 0.f;
      }
      e[j] = ev;
      s = s + ev;
    }
#pragma unroll
    for (int m = 1; m < 64; m <<= 1) {
      s.x += __shfl_xor(s.x, m, 64);
      s.y += __shfl_xor(s.y, m, 64);
    }
    float rA = 1.0f / s.x, rB = 1.0f / s.y;
#pragma unroll
    for (int j = 0; j < 16; j++)
      prob[j] = fmaf(e[j].x, rA, fmaf(e[j].y, rB, prob[j]));
  }

#pragma unroll
  for (int j = 0; j < 16; j++)
    pbuf[w][j * 64 + lane] = prob[j];
  __syncthreads();
#pragma unroll
  for (int k = 0; k < 2; k++) {
    int c = tid + k * 512;
    if (c < 1000) {
      float sm = (pbuf[0][c] + pbuf[1][c]) + (pbuf[2][c] + pbuf[3][c])
               + (pbuf[4][c] + pbuf[5][c]) + (pbuf[6][c] + pbuf[7][c]);
      out0[cb + c] = __expf(sm * 0.03125f);
    }
  }
}

// ---------------- launch ----------------
extern "C" void kernel_launch(void* const* d_in, const int* in_sizes, int n_in,
                              void* d_out, int out_size, void* d_ws, size_t ws_size,
                              hipStream_t stream) {
  const float* x = (const float*)d_in[0];   // 4096*1024
  const float* W = (const float*)d_in[1];   // 2000*1024
  float* out = (float*)d_out;               // [mu_out | sigma], each 4096000

  unsigned short* xh = (unsigned short*)d_ws;                        //  8,388,608 B
  unsigned short* wh = (unsigned short*)((char*)d_ws + 8388608);     //  4,194,304 B
  float*          mu = (float*)((char*)d_ws + 12582912);             // 16,384,000 B
  float* sigma = out + NC_TOT;

  convert_kernel<<<6144, 256, 0, stream>>>(x, W, xh, wh);
  dim3 g2(16, 32);
  gemm_kernel<<<g2, 256, 0, stream>>>(xh, wh, mu, sigma);
  sample_kernel<<<4096, 512, 0, stream>>>(mu, sigma, out);
}

// Round 5
// 327.057 us; speedup vs baseline: 1.0358x; 1.0358x over previous
//
#include <hip/hip_runtime.h>

// Problem: N=4096, D=1024, C=1000, T=32
//   h = x @ W^T  (4096 x 2000), mu = h[:, :1000], logvar = h[:, 1000:]
//   sigma = exp(0.5*logvar)
//   eps = jax.random.normal(key(42), (32,4096,1000))  -- threefry2x32, bit-exact
//   prob = mean_t softmax(mu + sigma*eps), out0 = exp(prob), out1 = sigma

typedef __attribute__((ext_vector_type(8))) _Float16 f16x8;
typedef __attribute__((ext_vector_type(4))) float f32x4;
typedef __attribute__((ext_vector_type(2))) float f32x2;

#define NC_TOT  4096000
#define H_HALF  65536000u   // half of T*N*C = 131072000

// ---------------- fp32 -> fp16 (RNE) ----------------
__device__ __forceinline__ unsigned short f2h(float f) {
  _Float16 h = (_Float16)f;
  return __builtin_bit_cast(unsigned short, h);
}

__global__ __launch_bounds__(256) void convert_kernel(
    const float* __restrict__ x, const float* __restrict__ W,
    unsigned short* __restrict__ xh, unsigned short* __restrict__ wh) {
  int qid = blockIdx.x * 256 + threadIdx.x;
  if (qid < 1048576) {                        // x: 4096*1024/4
    float4 v = ((const float4*)x)[qid];
    ((ushort4*)xh)[qid] = make_ushort4(f2h(v.x), f2h(v.y), f2h(v.z), f2h(v.w));
  } else {
    int q = qid - 1048576;                    // padded W quad index, < 524288
    int row = q >> 8;
    ushort4 o;
    if (row < 2000) {
      float4 v = ((const float4*)W)[q];
      o = make_ushort4(f2h(v.x), f2h(v.y), f2h(v.z), f2h(v.w));
    } else {
      o = make_ushort4(0, 0, 0, 0);
    }
    ((ushort4*)wh)[q] = o;
  }
}

// ---------------- fp16 MFMA GEMM, m97 structure (unchanged) ----------------
#define BK 32

typedef __attribute__((address_space(3))) unsigned char lds_byte;
typedef __attribute__((address_space(1))) unsigned char glb_byte;

__device__ __forceinline__ void glds16(const unsigned short* g, unsigned short* l) {
  __builtin_amdgcn_global_load_lds((const glb_byte*)g, (lds_byte*)l, 16, 0, 0);
}

__global__ __launch_bounds__(256) void gemm_kernel(
    const unsigned short* __restrict__ Ah,    // [4096][1024] fp16 bits
    const unsigned short* __restrict__ Bh,    // [2048][1024] fp16 bits, padded
    float* __restrict__ mu,                   // [4096][1000]
    float* __restrict__ sigma_out) {          // d_out + NC_TOT
  const int K = 1024;
  __shared__ unsigned short As[128 * BK];
  __shared__ unsigned short Bs[128 * BK];

  int tid  = threadIdx.x;
  int bx   = blockIdx.x;
  int by   = blockIdx.y;
  int w    = tid >> 6;
  int lane = tid & 63;
  int wr   = (w >> 1) * 64;
  int wc   = (w & 1) * 64;
  int lrow = lane & 15;
  int kq   = lane >> 4;

  f32x4 acc[4][4];
  for (int i = 0; i < 4; i++)
    for (int j = 0; j < 4; j++) acc[i][j] = (f32x4){0.f, 0.f, 0.f, 0.f};

  int srow = w * 16 + (lane >> 2);
  int scol = (lane & 3) * 8;
  const unsigned short* Ap = Ah + (by * 128 + srow) * K + scol;
  const unsigned short* Bp = Bh + (bx * 128 + srow) * K + scol;
  unsigned short* lA = As + w * 512;
  unsigned short* lB = Bs + w * 512;

  for (int kk = 0; kk < K; kk += BK) {
    __syncthreads();
    glds16(Ap + kk,            lA);
    glds16(Ap + kk + 64 * K,   lA + 2048);
    glds16(Bp + kk,            lB);
    glds16(Bp + kk + 64 * K,   lB + 2048);
    __syncthreads();

    f16x8 a[4], b[4];
    for (int i = 0; i < 4; i++)
      a[i] = *(const f16x8*)(As + (wr + i * 16 + lrow) * BK + kq * 8);
    for (int j = 0; j < 4; j++)
      b[j] = *(const f16x8*)(Bs + (wc + j * 16 + lrow) * BK + kq * 8);
    for (int i = 0; i < 4; i++)
      for (int j = 0; j < 4; j++)
        acc[i][j] = __builtin_amdgcn_mfma_f32_16x16x32_f16(a[i], b[j], acc[i][j], 0, 0, 0);
  }

  int orow0 = by * 128 + wr + (lane >> 4) * 4;
  int ocol0 = bx * 128 + wc + (lane & 15);
  for (int i = 0; i < 4; i++) {
    for (int j = 0; j < 4; j++) {
      int c = ocol0 + j * 16;
      for (int v = 0; v < 4; v++) {
        int r = orow0 + i * 16 + v;
        float val = acc[i][j][v];
        if (c < 1000)       mu[r * 1000 + c] = val;
        else if (c < 2000)  sigma_out[r * 1000 + (c - 1000)] = __expf(0.5f * val);
      }
    }
  }
}

// ---------------- threefry2x32, key = (0, 42) ----------------
__device__ __forceinline__ void threefry(unsigned x0, unsigned x1,
                                         unsigned& o0, unsigned& o1) {
  const unsigned ks1 = 42u;
  const unsigned ks2 = 0x1BD11BDAu ^ 42u;
#define TF_RND(r) { x0 += x1; x1 = (x1 << (r)) | (x1 >> (32 - (r))); x1 ^= x0; }
  x1 += ks1;
  TF_RND(13) TF_RND(15) TF_RND(26) TF_RND(6)
  x0 += ks1;  x1 += ks2 + 1u;
  TF_RND(17) TF_RND(29) TF_RND(16) TF_RND(24)
  x0 += ks2;  x1 += 2u;
  TF_RND(13) TF_RND(15) TF_RND(26) TF_RND(6)
  x1 += ks1 + 3u;
  TF_RND(17) TF_RND(29) TF_RND(16) TF_RND(24)
  x0 += ks1;  x1 += ks2 + 4u;
  TF_RND(13) TF_RND(15) TF_RND(26) TF_RND(6)
  x0 += ks2;  x1 += 5u;
#undef TF_RND
  o0 = x0; o1 = x1;
}

__device__ __forceinline__ float erfinv_big(float x, float w) {
  float v = __fsqrt_rn(w) - 3.0f;
  float p = -0.000200214257f;
  p = fmaf(p, v, 0.000100950558f);
  p = fmaf(p, v, 0.00134934322f);
  p = fmaf(p, v, -0.00367342844f);
  p = fmaf(p, v, 0.00573950773f);
  p = fmaf(p, v, -0.0076224613f);
  p = fmaf(p, v, 0.00943887047f);
  p = fmaf(p, v, 1.00167406f);
  p = fmaf(p, v, 2.83297682f);
  return 1.41421356f * (p * x);
}

__device__ __forceinline__ f32x2 splat2(float c) { return (f32x2){c, c}; }

__device__ __forceinline__ f32x2 normal2(f32x2 x) {
  f32x2 t = __builtin_elementwise_fma(-x, x, splat2(1.0f));
  f32x2 lg;
  lg.x = __builtin_amdgcn_logf(t.x);
  lg.y = __builtin_amdgcn_logf(t.y);
  f32x2 w = lg * splat2(-0.69314718f);
  f32x2 v = w - splat2(2.5f);
  f32x2 p = splat2(2.81022636e-08f);
  p = __builtin_elementwise_fma(p, v, splat2(3.43273939e-07f));
  p = __builtin_elementwise_fma(p, v, splat2(-3.5233877e-06f));
  p = __builtin_elementwise_fma(p, v, splat2(-4.39150654e-06f));
  p = __builtin_elementwise_fma(p, v, splat2(0.00021858087f));
  p = __builtin_elementwise_fma(p, v, splat2(-0.00125372503f));
  p = __builtin_elementwise_fma(p, v, splat2(-0.00417768164f));
  p = __builtin_elementwise_fma(p, v, splat2(0.246640727f));
  p = __builtin_elementwise_fma(p, v, splat2(1.50140941f));
  f32x2 r = (p * x) * splat2(1.41421356f);
  if (w.x >= 5.0f) r.x = erfinv_big(x.x, w.x);   // rare (~0.34%/sample)
  if (w.y >= 5.0f) r.y = erfinv_big(x.y, w.y);
  return r;
}

__device__ __forceinline__ f32x2 bits_to_u2(unsigned b0, unsigned b1) {
  f32x2 f;
  f.x = __builtin_bit_cast(float, (b0 >> 9) | 0x3f800000u);
  f.y = __builtin_bit_cast(float, (b1 >> 9) | 0x3f800000u);
  f = f - splat2(1.0f);
  return __builtin_elementwise_fma(f, splat2(2.0f), splat2(-0.99999994f));
}

// ---------------- sampling ----------------
// 512 thr = 8 waves per row n. Wave (g = w&3, h = w>>2): t-group g, class-half h.
// Round r: t-pair p = r*4+g (samples p, p+16); wave covers classes
// [h*512, h*512+512) in 8 chunks of 64. Per-wave reg state: e[8] + prob[8]
// (~48 live) -> no forced launch bounds, no spill (round-4 lesson).
// Cross-wave denominator via double-buffered LDS exchange: 1 barrier/round.
__global__ __launch_bounds__(512) void sample_kernel(
    const float* __restrict__ mu,      // ws
    const float* __restrict__ sigma,   // d_out + NC
    float* __restrict__ out0) {        // d_out
  int n    = blockIdx.x;
  int tid  = threadIdx.x;
  int lane = tid & 63, w = tid >> 6;
  int g = w & 3, h = w >> 2;
  __shared__ float2 msb[1024];         // (mu, sigma), 8 KB
  __shared__ float2 red[2][4][2];      // [buf][g][h] -> (sumA, sumB)
  __shared__ float  pbuf[4][1024];     // per-group prob partials, 16 KB

  int cb = n * 1000;
#pragma unroll
  for (int k = 0; k < 2; k++) {
    int c = tid + k * 512;
    float2 v;
    if (c < 1000) { v.x = mu[cb + c]; v.y = sigma[cb + c]; }
    else          { v.x = 0.f;        v.y = 0.f; }
    msb[c] = v;
  }
  __syncthreads();

  float prob[8];
#pragma unroll
  for (int j = 0; j < 8; j++) prob[j] = 0.f;
  int cofs = h * 512 + lane;

#pragma unroll 1
  for (int r = 0; r < 4; r++) {
    int p = r * 4 + g;
    unsigned ib = (unsigned)(p * 4096000 + cb + h * 512) + (unsigned)lane;
    f32x2 e[8];
    f32x2 s = splat2(0.f);
#pragma unroll
    for (int j = 0; j < 8; j++) {
      float2 ms = msb[cofs + j * 64];
      unsigned i0 = ib + (unsigned)(j * 64);
      unsigned o0, o1;
      threefry(i0, i0 + H_HALF, o0, o1);
      f32x2 eps = normal2(bits_to_u2(o0, o1));
      f32x2 lg = __builtin_elementwise_fma(splat2(ms.y), eps, splat2(ms.x));
      f32x2 ev;
      ev.x = __expf(lg.x);                       // sample p
      ev.y = __expf(lg.y);                       // sample p+16
      if (h == 1 && j == 7) {                    // classes >= 1000 are padding
        ev.x = (lane < 40) ? ev.x : 0.f;
        ev.y = (lane < 40) ? ev.y : 0.f;
      }
      e[j] = ev;
      s = s + ev;
    }
#pragma unroll
    for (int m = 1; m < 64; m <<= 1) {
      s.x += __shfl_xor(s.x, m, 64);
      s.y += __shfl_xor(s.y, m, 64);
    }
    if (lane == 0) red[r & 1][g][h] = make_float2(s.x, s.y);
    __syncthreads();                   // double-buffered: WAR-safe (see note)
    float2 p0 = red[r & 1][g][0];
    float2 p1 = red[r & 1][g][1];
    float rA = 1.0f / (p0.x + p1.x);
    float rB = 1.0f / (p0.y + p1.y);
#pragma unroll
    for (int j = 0; j < 8; j++)
      prob[j] = fmaf(e[j].x, rA, fmaf(e[j].y, rB, prob[j]));
  }
  // WAR note: round r writes red[r&1]; the next write to that buffer is in
  // round r+2, which is ordered after round r+1's block-wide barrier, which
  // is ordered after every wave's round-r read. No race.

#pragma unroll
  for (int j = 0; j < 8; j++)
    pbuf[g][h * 512 + j * 64 + lane] = prob[j];
  __syncthreads();
#pragma unroll
  for (int k = 0; k < 2; k++) {
    int c = tid + k * 512;
    if (c < 1000) {
      float sm = (pbuf[0][c] + pbuf[1][c]) + (pbuf[2][c] + pbuf[3][c]);
      out0[cb + c] = __expf(sm * 0.03125f);
    }
  }
}

// ---------------- launch ----------------
extern "C" void kernel_launch(void* const* d_in, const int* in_sizes, int n_in,
                              void* d_out, int out_size, void* d_ws, size_t ws_size,
                              hipStream_t stream) {
  const float* x = (const float*)d_in[0];   // 4096*1024
  const float* W = (const float*)d_in[1];   // 2000*1024
  float* out = (float*)d_out;               // [mu_out | sigma], each 4096000

  unsigned short* xh = (unsigned short*)d_ws;                        //  8,388,608 B
  unsigned short* wh = (unsigned short*)((char*)d_ws + 8388608);     //  4,194,304 B
  float*          mu = (float*)((char*)d_ws + 12582912);             // 16,384,000 B
  float* sigma = out + NC_TOT;

  convert_kernel<<<6144, 256, 0, stream>>>(x, W, xh, wh);
  dim3 g2(16, 32);
  gemm_kernel<<<g2, 256, 0, stream>>>(xh, wh, mu, sigma);
  sample_kernel<<<4096, 512, 0, stream>>>(mu, sigma, out);
}

// Round 6
// 292.401 us; speedup vs baseline: 1.1585x; 1.1185x over previous
//
#include <hip/hip_runtime.h>

// Problem: N=4096, D=1024, C=1000, T=32
//   h = x @ W^T  (4096 x 2000), mu = h[:, :1000], logvar = h[:, 1000:]
//   sigma = exp(0.5*logvar)
//   eps = jax.random.normal(key(42), (32,4096,1000))  -- threefry2x32, bit-exact
//   prob = mean_t softmax(mu + sigma*eps), out0 = exp(prob), out1 = sigma

typedef __attribute__((ext_vector_type(8))) _Float16 f16x8;
typedef __attribute__((ext_vector_type(4))) float f32x4;
typedef __attribute__((ext_vector_type(2))) float f32x2;

#define NC_TOT  4096000
#define H_HALF  65536000u   // half of T*N*C = 131072000

// ---------------- fp32 -> fp16 (RNE) ----------------
__device__ __forceinline__ unsigned short f2h(float f) {
  _Float16 h = (_Float16)f;
  return __builtin_bit_cast(unsigned short, h);
}

__global__ __launch_bounds__(256) void convert_kernel(
    const float* __restrict__ x, const float* __restrict__ W,
    unsigned short* __restrict__ xh, unsigned short* __restrict__ wh) {
  int qid = blockIdx.x * 256 + threadIdx.x;
  if (qid < 1048576) {                        // x: 4096*1024/4
    float4 v = ((const float4*)x)[qid];
    ((ushort4*)xh)[qid] = make_ushort4(f2h(v.x), f2h(v.y), f2h(v.z), f2h(v.w));
  } else {
    int q = qid - 1048576;                    // padded W quad index, < 524288
    int row = q >> 8;
    ushort4 o;
    if (row < 2000) {
      float4 v = ((const float4*)W)[q];
      o = make_ushort4(f2h(v.x), f2h(v.y), f2h(v.z), f2h(v.w));
    } else {
      o = make_ushort4(0, 0, 0, 0);
    }
    ((ushort4*)wh)[q] = o;
  }
}

// ---------------- fp16 MFMA GEMM, m97 structure (unchanged) ----------------
#define BK 32

typedef __attribute__((address_space(3))) unsigned char lds_byte;
typedef __attribute__((address_space(1))) unsigned char glb_byte;

__device__ __forceinline__ void glds16(const unsigned short* g, unsigned short* l) {
  __builtin_amdgcn_global_load_lds((const glb_byte*)g, (lds_byte*)l, 16, 0, 0);
}

__global__ __launch_bounds__(256) void gemm_kernel(
    const unsigned short* __restrict__ Ah,    // [4096][1024] fp16 bits
    const unsigned short* __restrict__ Bh,    // [2048][1024] fp16 bits, padded
    float* __restrict__ mu,                   // [4096][1000]
    float* __restrict__ sigma_out) {          // d_out + NC_TOT
  const int K = 1024;
  __shared__ unsigned short As[128 * BK];
  __shared__ unsigned short Bs[128 * BK];

  int tid  = threadIdx.x;
  int bx   = blockIdx.x;
  int by   = blockIdx.y;
  int w    = tid >> 6;
  int lane = tid & 63;
  int wr   = (w >> 1) * 64;
  int wc   = (w & 1) * 64;
  int lrow = lane & 15;
  int kq   = lane >> 4;

  f32x4 acc[4][4];
  for (int i = 0; i < 4; i++)
    for (int j = 0; j < 4; j++) acc[i][j] = (f32x4){0.f, 0.f, 0.f, 0.f};

  int srow = w * 16 + (lane >> 2);
  int scol = (lane & 3) * 8;
  const unsigned short* Ap = Ah + (by * 128 + srow) * K + scol;
  const unsigned short* Bp = Bh + (bx * 128 + srow) * K + scol;
  unsigned short* lA = As + w * 512;
  unsigned short* lB = Bs + w * 512;

  for (int kk = 0; kk < K; kk += BK) {
    __syncthreads();
    glds16(Ap + kk,            lA);
    glds16(Ap + kk + 64 * K,   lA + 2048);
    glds16(Bp + kk,            lB);
    glds16(Bp + kk + 64 * K,   lB + 2048);
    __syncthreads();

    f16x8 a[4], b[4];
    for (int i = 0; i < 4; i++)
      a[i] = *(const f16x8*)(As + (wr + i * 16 + lrow) * BK + kq * 8);
    for (int j = 0; j < 4; j++)
      b[j] = *(const f16x8*)(Bs + (wc + j * 16 + lrow) * BK + kq * 8);
    for (int i = 0; i < 4; i++)
      for (int j = 0; j < 4; j++)
        acc[i][j] = __builtin_amdgcn_mfma_f32_16x16x32_f16(a[i], b[j], acc[i][j], 0, 0, 0);
  }

  int orow0 = by * 128 + wr + (lane >> 4) * 4;
  int ocol0 = bx * 128 + wc + (lane & 15);
  for (int i = 0; i < 4; i++) {
    for (int j = 0; j < 4; j++) {
      int c = ocol0 + j * 16;
      for (int v = 0; v < 4; v++) {
        int r = orow0 + i * 16 + v;
        float val = acc[i][j][v];
        if (c < 1000)       mu[r * 1000 + c] = val;
        else if (c < 2000)  sigma_out[r * 1000 + (c - 1000)] = __expf(0.5f * val);
      }
    }
  }
}

// ---------------- threefry2x32 x2, key = (0,42), source-interleaved ----------------
// Two independent hash chains interleaved: chain dep latency (4 cyc) covered by
// 2-cyc issue of the sibling chain. ROTL forced to v_alignbit_b32 (1 op).
#define ROTL(x, r) __builtin_amdgcn_alignbit((x), (x), 32 - (r))

__device__ __forceinline__ void threefry2(unsigned a, unsigned b,
                                          unsigned& oa0, unsigned& oa1,
                                          unsigned& ob0, unsigned& ob1) {
  const unsigned ks1 = 42u;
  const unsigned ks2 = 0x1BD11BDAu ^ 42u;
  unsigned xa0 = a, xa1 = a + H_HALF + ks1;   // x1 = ctr_hi; x1 += ks1 (folded)
  unsigned xb0 = b, xb1 = b + H_HALF + ks1;
#define TF2(r) { xa0 += xa1; xb0 += xb1; \
                 xa1 = ROTL(xa1, r) ^ xa0; xb1 = ROTL(xb1, r) ^ xb0; }
  TF2(13) TF2(15) TF2(26) TF2(6)
  xa0 += ks1; xa1 += ks2 + 1u;  xb0 += ks1; xb1 += ks2 + 1u;
  TF2(17) TF2(29) TF2(16) TF2(24)
  xa0 += ks2; xa1 += 2u;        xb0 += ks2; xb1 += 2u;
  TF2(13) TF2(15) TF2(26) TF2(6)
  xa1 += ks1 + 3u;              xb1 += ks1 + 3u;
  TF2(17) TF2(29) TF2(16) TF2(24)
  xa0 += ks1; xa1 += ks2 + 4u;  xb0 += ks1; xb1 += ks2 + 4u;
  TF2(13) TF2(15) TF2(26) TF2(6)
  xa0 += ks2; xa1 += 5u;        xb0 += ks2; xb1 += 5u;
#undef TF2
  oa0 = xa0; oa1 = xa1; ob0 = xb0; ob1 = xb1;
}

__device__ __forceinline__ float erfinv_big(float x, float w) {
  float v = __fsqrt_rn(w) - 3.0f;
  float p = -0.000200214257f;
  p = fmaf(p, v, 0.000100950558f);
  p = fmaf(p, v, 0.00134934322f);
  p = fmaf(p, v, -0.00367342844f);
  p = fmaf(p, v, 0.00573950773f);
  p = fmaf(p, v, -0.0076224613f);
  p = fmaf(p, v, 0.00943887047f);
  p = fmaf(p, v, 1.00167406f);
  p = fmaf(p, v, 2.83297682f);
  return 1.41421356f * (p * x);
}

__device__ __forceinline__ f32x4 splat4(float c) { return (f32x4){c, c, c, c}; }

// 4-wide uniform + erfinv: 4 independent lanes -> FMA-chain ILP=4.
// Per-component math identical to the scalar/2-wide versions of prior rounds.
__device__ __forceinline__ f32x4 bits_to_u4(unsigned b0, unsigned b1,
                                            unsigned b2, unsigned b3) {
  f32x4 f;
  f.x = __builtin_bit_cast(float, (b0 >> 9) | 0x3f800000u);
  f.y = __builtin_bit_cast(float, (b1 >> 9) | 0x3f800000u);
  f.z = __builtin_bit_cast(float, (b2 >> 9) | 0x3f800000u);
  f.w = __builtin_bit_cast(float, (b3 >> 9) | 0x3f800000u);
  f = f - splat4(1.0f);
  return __builtin_elementwise_fma(f, splat4(2.0f), splat4(-0.99999994f));
}

__device__ __forceinline__ f32x4 normal4(f32x4 x) {
  f32x4 t = __builtin_elementwise_fma(-x, x, splat4(1.0f));
  f32x4 lg;
  lg.x = __builtin_amdgcn_logf(t.x);
  lg.y = __builtin_amdgcn_logf(t.y);
  lg.z = __builtin_amdgcn_logf(t.z);
  lg.w = __builtin_amdgcn_logf(t.w);
  f32x4 w = lg * splat4(-0.69314718f);
  f32x4 v = w - splat4(2.5f);
  f32x4 p = splat4(2.81022636e-08f);
  p = __builtin_elementwise_fma(p, v, splat4(3.43273939e-07f));
  p = __builtin_elementwise_fma(p, v, splat4(-3.5233877e-06f));
  p = __builtin_elementwise_fma(p, v, splat4(-4.39150654e-06f));
  p = __builtin_elementwise_fma(p, v, splat4(0.00021858087f));
  p = __builtin_elementwise_fma(p, v, splat4(-0.00125372503f));
  p = __builtin_elementwise_fma(p, v, splat4(-0.00417768164f));
  p = __builtin_elementwise_fma(p, v, splat4(0.246640727f));
  p = __builtin_elementwise_fma(p, v, splat4(1.50140941f));
  f32x4 r = (p * x) * splat4(1.41421356f);
  if (w.x >= 5.0f) r.x = erfinv_big(x.x, w.x);   // rare (~0.34%/sample)
  if (w.y >= 5.0f) r.y = erfinv_big(x.y, w.y);
  if (w.z >= 5.0f) r.z = erfinv_big(x.z, w.z);
  if (w.w >= 5.0f) r.w = erfinv_big(x.w, w.w);
  return r;
}

// ---------------- sampling ----------------
// Round-2 shape (best so far): 256 thr = 4 waves per row n, wave w owns t-pairs
// 4w..4w+3, no in-loop barriers. mu/sigma in LDS (frees 32 regs/wave).
// Inner loop: chunk PAIRS -> two interleaved threefry chains + 4-wide float
// pipeline. e4 layout: (eA_j0, eB_j0, eA_j1, eB_j1).
__global__ __launch_bounds__(256) void sample_kernel(
    const float* __restrict__ mu,      // ws
    const float* __restrict__ sigma,   // d_out + NC
    float* __restrict__ out0) {        // d_out
  int n    = blockIdx.x;
  int tid  = threadIdx.x;
  int lane = tid & 63, w = tid >> 6;
  __shared__ float2 msb[1024];         // (mu, sigma), 8 KB
  __shared__ float  pbuf[4][1024];     // per-wave prob partials, 16 KB

  int cb = n * 1000;
#pragma unroll
  for (int k = 0; k < 4; k++) {
    int c = tid + k * 256;
    float2 v;
    if (c < 1000) { v.x = mu[cb + c]; v.y = sigma[cb + c]; }
    else          { v.x = 0.f;        v.y = 0.f; }
    msb[c] = v;
  }
  __syncthreads();

  float prob[16];
#pragma unroll
  for (int j = 0; j < 16; j++) prob[j] = 0.f;

  f32x4 e4[8];
#pragma unroll 1
  for (int it = 0; it < 4; it++) {
    int t = w * 4 + it;
    unsigned ib = (unsigned)(t * 4096000 + cb) + (unsigned)lane;
    f32x4 s4 = splat4(0.f);
#pragma unroll
    for (int jj = 0; jj < 8; jj++) {
      int j0 = jj * 2, j1 = jj * 2 + 1;
      float2 ms0 = msb[j0 * 64 + lane];          // stride-2 banks: free 2-way
      float2 ms1 = msb[j1 * 64 + lane];
      unsigned i0 = ib + (unsigned)(j0 * 64);
      unsigned o00, o01, o10, o11;
      threefry2(i0, i0 + 64u, o00, o01, o10, o11);
      f32x4 eps = normal4(bits_to_u4(o00, o01, o10, o11));
      f32x4 mu4 = (f32x4){ms0.x, ms0.x, ms1.x, ms1.x};
      f32x4 sg4 = (f32x4){ms0.y, ms0.y, ms1.y, ms1.y};
      f32x4 lgt = __builtin_elementwise_fma(sg4, eps, mu4);
      f32x4 ev;
      ev.x = __expf(lgt.x);                      // chunk j0, sample t
      ev.y = __expf(lgt.y);                      // chunk j0, sample t+16
      ev.z = __expf(lgt.z);                      // chunk j1, sample t
      ev.w = __expf(lgt.w);                      // chunk j1, sample t+16
      if (jj == 7) {                             // classes >= 1000 (chunk 15)
        ev.z = (lane < 40) ? ev.z : 0.f;
        ev.w = (lane < 40) ? ev.w : 0.f;
      }
      e4[jj] = ev;
      s4 = s4 + ev;
    }
    float sA = s4.x + s4.z, sB = s4.y + s4.w;
#pragma unroll
    for (int m = 1; m < 64; m <<= 1) {
      sA += __shfl_xor(sA, m, 64);
      sB += __shfl_xor(sB, m, 64);
    }
    float rA = 1.0f / sA, rB = 1.0f / sB;
#pragma unroll
    for (int jj = 0; jj < 8; jj++) {
      prob[jj * 2]     = fmaf(e4[jj].x, rA, fmaf(e4[jj].y, rB, prob[jj * 2]));
      prob[jj * 2 + 1] = fmaf(e4[jj].z, rA, fmaf(e4[jj].w, rB, prob[jj * 2 + 1]));
    }
  }

#pragma unroll
  for (int j = 0; j < 16; j++)
    pbuf[w][j * 64 + lane] = prob[j];
  __syncthreads();
#pragma unroll
  for (int k = 0; k < 4; k++) {
    int c = tid + k * 256;
    if (c < 1000) {
      float sm = (pbuf[0][c] + pbuf[1][c]) + (pbuf[2][c] + pbuf[3][c]);
      out0[cb + c] = __expf(sm * 0.03125f);
    }
  }
}

// ---------------- launch ----------------
extern "C" void kernel_launch(void* const* d_in, const int* in_sizes, int n_in,
                              void* d_out, int out_size, void* d_ws, size_t ws_size,
                              hipStream_t stream) {
  const float* x = (const float*)d_in[0];   // 4096*1024
  const float* W = (const float*)d_in[1];   // 2000*1024
  float* out = (float*)d_out;               // [mu_out | sigma], each 4096000

  unsigned short* xh = (unsigned short*)d_ws;                        //  8,388,608 B
  unsigned short* wh = (unsigned short*)((char*)d_ws + 8388608);     //  4,194,304 B
  float*          mu = (float*)((char*)d_ws + 12582912);             // 16,384,000 B
  float* sigma = out + NC_TOT;

  convert_kernel<<<6144, 256, 0, stream>>>(x, W, xh, wh);
  dim3 g2(16, 32);
  gemm_kernel<<<g2, 256, 0, stream>>>(xh, wh, mu, sigma);
  sample_kernel<<<4096, 256, 0, stream>>>(mu, sigma, out);
}